// Round 5
// baseline (384.808 us; speedup 1.0000x reference)
//
#include <hip/hip_runtime.h>

// SelectionGNN clique+line. I/O: float32. Internals: bf16 end-to-end with f32
// accumulation (MFMA + reduce). B=8, N=4096, E=1, K=3, F=[16,32,16],
// MLP 65536->64->1.
// R11: cvt3 restructured around the stream-count theory: R8-R10 all ran
//     ~2080 resident blocks x 8 tiny iters (one giant burst, thousands of
//     interleaved 16B streams -> ~2.2 TB/s). Now 520 blocks (256 Sc / 256 Sl
//     / 8 x, resolved once), each streaming 32 contiguous chunks (256 KB)
//     with a depth-4 asm load pipeline (8 dwordx4 in flight) and exact
//     counted vmcnt waits. Few long ordered streams ~= what the 6.6 TB/s
//     harness fill does. Everything else identical to R10.

#define NN 4096
#define BB 8

typedef unsigned short u16;
typedef unsigned int   u32;

typedef __attribute__((ext_vector_type(8))) short bf16x8;  // 8 bf16 = 4 VGPRs
typedef __attribute__((ext_vector_type(4))) float f32x4;

__device__ __forceinline__ u16 f2bf(float f) {
    union { float f; u32 i; } c; c.f = f;
    u32 i = c.i;
    u32 r = (i + 0x7FFFu + ((i >> 16) & 1u)) >> 16;  // RTNE
    return (u16)r;
}
__device__ __forceinline__ float bf2f(u16 u) {
    union { u32 i; float f; } c; c.i = ((u32)u) << 16; return c.f;
}
__device__ __forceinline__ u32 pack2bf(float lo, float hi) {
    return (u32)f2bf(lo) | ((u32)f2bf(hi) << 16);
}

__device__ __forceinline__ void gload_lds16(const u16* g, u16* l) {
    __builtin_amdgcn_global_load_lds(
        (__attribute__((address_space(1))) void*)g,
        (__attribute__((address_space(3))) void*)l, 16, 0, 0);
}

__device__ __forceinline__ void aload16(f32x4& dst, const float* src) {
    asm volatile("global_load_dwordx4 %0, %1, off"
                 : "=v"(dst) : "v"(src) : "memory");
}

// ---------------------------------------------------------------------------
// Fused f32 -> bf16 conversion of Sc (16M f), Sl (16M f), x (512K f).
// 520 blocks: 0..255 -> Sc, 256..511 -> Sl, 512..519 -> x (resolved once,
// wave-uniform; region sizes align exactly: 8192/32=256, 256/32=8).
// Each block streams 32 contiguous chunks of 2048 floats (256 KB span).
// Depth-4 pipeline: 8 asm dwordx4 in flight; exact counted vmcnt schedule
// (stores count in vmcnt): wait(i) = 6,7,8,9...9,7,5,3. sched_barrier(0)
// after each wait keeps register-only packs from hoisting above it (#18).
// ---------------------------------------------------------------------------
__global__ __launch_bounds__(256) void cvt3(const float* __restrict__ a, u16* __restrict__ da,
                                            const float* __restrict__ b, u16* __restrict__ db,
                                            const float* __restrict__ c, u16* __restrict__ dc)
{
    const int t8  = threadIdx.x * 8;
    const int blk = blockIdx.x;     // 0..519

    const float* s; u16* d;
    if (blk < 256)      { s = a + (size_t)blk * 65536;         d = da + (size_t)blk * 65536; }
    else if (blk < 512) { s = b + (size_t)(blk - 256) * 65536; d = db + (size_t)(blk - 256) * 65536; }
    else                { s = c + (size_t)(blk - 512) * 65536; d = dc + (size_t)(blk - 512) * 65536; }
    s += t8;
    d += t8;

    f32x4 va[4], vb[4];
#pragma unroll
    for (int i = 0; i < 4; ++i) {
        aload16(va[i], s + i * 2048);
        aload16(vb[i], s + i * 2048 + 4);
    }

#pragma unroll
    for (int i = 0; i < 32; ++i) {
        // exact counted wait so chunk i's two loads have landed
        // (FIFO holds newer: 6 loads of chunks i+1..i+3 + up to 3 stores)
        if (i == 0)       asm volatile("s_waitcnt vmcnt(6)" ::: "memory");
        else if (i == 1)  asm volatile("s_waitcnt vmcnt(7)" ::: "memory");
        else if (i == 2)  asm volatile("s_waitcnt vmcnt(8)" ::: "memory");
        else if (i <= 28) asm volatile("s_waitcnt vmcnt(9)" ::: "memory");
        else if (i == 29) asm volatile("s_waitcnt vmcnt(7)" ::: "memory");
        else if (i == 30) asm volatile("s_waitcnt vmcnt(5)" ::: "memory");
        else              asm volatile("s_waitcnt vmcnt(3)" ::: "memory");
        __builtin_amdgcn_sched_barrier(0);     // keep packs below the wait

        const f32x4 x0 = va[i % 4];
        const f32x4 x1 = vb[i % 4];
        uint4 o;
        o.x = pack2bf(x0[0], x0[1]); o.y = pack2bf(x0[2], x0[3]);
        o.z = pack2bf(x1[0], x1[1]); o.w = pack2bf(x1[2], x1[3]);
        *(uint4*)(d + i * 2048) = o;

        if (i + 4 < 32) {
            aload16(va[i % 4], s + (i + 4) * 2048);
            aload16(vb[i % 4], s + (i + 4) * 2048 + 4);
        }
    }
}

// ---------------------------------------------------------------------------
// Split-K diffusion, 128(M) x 64(N) tile, BK=64, bf16 A/B via async LDS:
//   Part[kz][r,n] = sum_{k in slice} Z[r,k] * S[n,k]   (bf16 partial planes)
// LDS unpadded, XOR-swizzled 16B granules: slot(r,g) = g ^ (r&7).
// Pipeline (depth 2, 3 buffers, 72 KB -> 2 blocks/CU = grid co-residency):
//   per iter i: STAGE(i+2) ; s_waitcnt vmcnt(12) ; s_barrier ; COMPUTE(i) ;
//   s_barrier.  Counted vmcnt keeps 2 staged tiles in flight across barriers
//   (T4). Fully unrolled via template ITERS (8 or 16).
// Epilogue: per-wave LDS transpose (stride 72 u16, 16B-aligned rows) then
// 4x global_store_dwordx4 per lane.
// grid: (64, M/128, KS). blockIdx.x XCD-swizzled. 4 waves stacked in M; wave
// owns 32x64 via 2x4 mfma_f32_16x16x32_bf16.
// ---------------------------------------------------------------------------
template <int ITERS>
__global__ __launch_bounds__(256) void diffuse(const u16* __restrict__ Z,
                                               const u16* __restrict__ S,
                                               u16* __restrict__ Part)
{
    __shared__ u16 As[3 * 128 * 64];   // 3 x 16 KB, swizzled
    __shared__ u16 Bs[3 * 64 * 64];    // 3 x  8 KB, swizzled

    const int bx    = blockIdx.x;                   // 0..63
    const int ntile = ((bx & 7) << 3) | (bx >> 3);  // XCD swizzle
    const int nBase = ntile * 64;
    const int mBase = blockIdx.y * 128;
    const int tid   = threadIdx.x;
    const int lane  = tid & 63;
    const int wv    = tid >> 6;
    const int quad  = lane >> 4;
    const int l16   = lane & 15;

    const int kStart = (int)blockIdx.z * (ITERS * 64);

    // async staging: wave-issue = 64 lanes x 16 B = 8 rows x 8 granules
    const int rl   = lane >> 3;        // row within 8-row group
    const int gsl  = lane & 7;         // dest granule slot
    const int gsrc = gsl ^ rl;         // source granule (XOR swizzle)

    f32x4 acc[2][4];
#pragma unroll
    for (int i = 0; i < 2; ++i)
#pragma unroll
        for (int j = 0; j < 4; ++j) acc[i][j] = (f32x4){0.f, 0.f, 0.f, 0.f};

    auto stage = [&](int buf, int k0) {
#pragma unroll
        for (int j = 0; j < 4; ++j) {
            const int rb = (wv * 4 + j) * 8;   // 0..120
            gload_lds16(Z + (size_t)(mBase + rb + rl) * NN + k0 + gsrc * 8,
                        &As[buf * 8192 + rb * 64]);
        }
#pragma unroll
        for (int j = 0; j < 2; ++j) {
            const int rb = (wv * 2 + j) * 8;   // 0..56
            gload_lds16(S + (size_t)(nBase + rb + rl) * NN + k0 + gsrc * 8,
                        &Bs[buf * 4096 + rb * 64]);
        }
    };

    auto compute = [&](int buf) {
#pragma unroll
        for (int s = 0; s < 2; ++s) {
            const int g = s * 4 + quad;        // k-granule 0..7
            bf16x8 af[2], bf[4];
#pragma unroll
            for (int mi = 0; mi < 2; ++mi) {
                const int r = wv * 32 + mi * 16 + l16;
                af[mi] = *(const bf16x8*)&As[buf * 8192 + r * 64 + ((g ^ (r & 7)) << 3)];
            }
#pragma unroll
            for (int ni = 0; ni < 4; ++ni) {
                const int r = ni * 16 + l16;
                bf[ni] = *(const bf16x8*)&Bs[buf * 4096 + r * 64 + ((g ^ (r & 7)) << 3)];
            }
#pragma unroll
            for (int mi = 0; mi < 2; ++mi)
#pragma unroll
                for (int ni = 0; ni < 4; ++ni)
                    acc[mi][ni] = __builtin_amdgcn_mfma_f32_16x16x32_bf16(
                        af[mi], bf[ni], acc[mi][ni], 0, 0, 0);
        }
    };

    // prologue: two tiles in flight before first wait
    stage(0, kStart);
    stage(1, kStart + 64);

#pragma unroll
    for (int i = 0; i < ITERS; ++i) {
        if (i + 2 < ITERS) stage((i + 2) % 3, kStart + (i + 2) * 64);
        if (i < ITERS - 2)
            asm volatile("s_waitcnt vmcnt(12)" ::: "memory");  // stage(i) landed
        else if (i == ITERS - 2)
            asm volatile("s_waitcnt vmcnt(6)" ::: "memory");
        else
            asm volatile("s_waitcnt vmcnt(0)" ::: "memory");
        __builtin_amdgcn_s_barrier();          // raw barrier: no vmcnt drain
        compute(i % 3);
        if (i + 1 < ITERS) __builtin_amdgcn_s_barrier();  // guard buf reuse
    }

    // Epilogue: all waves done with LDS reads before we reuse As as scratch.
    asm volatile("s_waitcnt lgkmcnt(0)" ::: "memory");
    __builtin_amdgcn_s_barrier();

    // Per-wave transpose region: 32 rows x 72 u16 (144B rows, 16B-aligned).
    // D mapping: col = lane&15, row = quad*4 + reg.
    u16* tb = &As[wv * 2304];
#pragma unroll
    for (int mi = 0; mi < 2; ++mi)
#pragma unroll
        for (int ni = 0; ni < 4; ++ni)
#pragma unroll
            for (int i = 0; i < 4; ++i)
                tb[(mi * 16 + quad * 4 + i) * 72 + ni * 16 + l16] =
                    f2bf(acc[mi][ni][i]);

    const size_t plane = (size_t)gridDim.y * 128 * NN;
    u16* pp = Part + (size_t)blockIdx.z * plane;
    const int row0g = mBase + wv * 32;
#pragma unroll
    for (int j = 0; j < 4; ++j) {
        const int r = (lane >> 3) + j * 8;      // 0..31
        const int c = (lane & 7) * 8;           // 0..56
        bf16x8 v = *(const bf16x8*)&tb[r * 72 + c];
        *(bf16x8*)&pp[(size_t)(row0g + r) * NN + nBase + c] = v;
    }
}

// ---------------------------------------------------------------------------
// Sum KS bf16 partial planes (f32 accumulate) -> bf16 z.  (z1 only.)
// Vectorized 8 bf16 (uint4) per thread-iter.
// ---------------------------------------------------------------------------
template <int KS>
__global__ __launch_bounds__(256) void reduce_part(const u16* __restrict__ part,
                                                   int planeElems,
                                                   u16* __restrict__ outb)
{
    const int base   = (blockIdx.x * 256 + threadIdx.x) * 8;
    const int stride = gridDim.x * 256 * 8;
    for (int i = base; i < planeElems; i += stride) {
        float s[8];
#pragma unroll
        for (int e = 0; e < 8; ++e) s[e] = 0.f;
#pragma unroll
        for (int p = 0; p < KS; ++p) {
            uint4 v = *(const uint4*)(part + (size_t)p * planeElems + i);
            const u32 w[4] = {v.x, v.y, v.z, v.w};
#pragma unroll
            for (int q = 0; q < 4; ++q) {
                union { u32 i; float f; } lo, hi;
                lo.i = w[q] << 16;
                hi.i = w[q] & 0xFFFF0000u;
                s[q * 2]     += lo.f;
                s[q * 2 + 1] += hi.f;
            }
        }
        uint4 o;
        o.x = (u32)f2bf(s[0]) | ((u32)f2bf(s[1]) << 16);
        o.y = (u32)f2bf(s[2]) | ((u32)f2bf(s[3]) << 16);
        o.z = (u32)f2bf(s[4]) | ((u32)f2bf(s[5]) << 16);
        o.w = (u32)f2bf(s[6]) | ((u32)f2bf(s[7]) << 16);
        *(uint4*)(outb + i) = o;
    }
}

// ---------------------------------------------------------------------------
// Tap combine + ReLU, bf16 in/out (f32 math). Tap 2 is read directly from
// the KS bf16 partial planes (fused reduce, f32-exact inside):
// out[b,g,n] = relu( bias[g] + sum_k sum_f W[g,k,f] * z_k[b,f,n] )
// ---------------------------------------------------------------------------
template <int FIN, int FOUT, int KS>
__global__ __launch_bounds__(256) void combine_relu(
    const u16* __restrict__ z0, const u16* __restrict__ z1,
    const u16* __restrict__ part2, int planeElems,
    const float* __restrict__ W, const float* __restrict__ bias,
    u16* __restrict__ out)
{
    __shared__ float hs[FOUT * 3 * FIN];
    __shared__ float bs[FOUT];
    for (int i = threadIdx.x; i < FOUT * 3 * FIN; i += 256) hs[i] = W[i];
    if (threadIdx.x < FOUT) bs[threadIdx.x] = bias[threadIdx.x];
    __syncthreads();

    const int nb = NN / 256;                 // 16
    const int b  = blockIdx.x / nb;
    const int n  = (blockIdx.x % nb) * 256 + threadIdx.x;

    float zv[3][FIN];
    const u16* zp0 = z0 + (size_t)b * FIN * NN + n;
    const u16* zp1 = z1 + (size_t)b * FIN * NN + n;
    const u16* zp2 = part2 + (size_t)b * FIN * NN + n;
#pragma unroll
    for (int f = 0; f < FIN; ++f) {
        zv[0][f] = bf2f(zp0[(size_t)f * NN]);
        zv[1][f] = bf2f(zp1[(size_t)f * NN]);
        float s = 0.f;
#pragma unroll
        for (int p = 0; p < KS; ++p)
            s += bf2f(zp2[(size_t)p * planeElems + (size_t)f * NN]);
        zv[2][f] = s;
    }

    u16* op = out + (size_t)b * FOUT * NN + n;
    for (int g = 0; g < FOUT; ++g) {
        float acc = bs[g];
#pragma unroll
        for (int k = 0; k < 3; ++k)
#pragma unroll
            for (int f = 0; f < FIN; ++f)
                acc = fmaf(hs[(g * 3 + k) * FIN + f], zv[k][f], acc);
        op[(size_t)g * NN] = f2bf(fmaxf(acc, 0.f));
    }
}

// ---------------------------------------------------------------------------
// MLP layer 1, split-K: h1p[slice][b][j] = sum_{slice} y[b,i]*Wm1[j,i].
// y is bf16; Wm1 f32. grid: (64, 8). Plain stores (no atomics, no memset);
// mlp2 sums the 8 slices and applies bias+ReLU.
// ---------------------------------------------------------------------------
__global__ __launch_bounds__(256) void mlp1(const u16* __restrict__ y,
                                            const float* __restrict__ Wm1,
                                            float* __restrict__ h1p)
{
    const int j    = blockIdx.x;
    const int base = blockIdx.y * 8192;
    const int D    = 16 * NN;  // 65536

    float acc[BB];
#pragma unroll
    for (int b = 0; b < BB; ++b) acc[b] = 0.f;

    const float* wrow = Wm1 + (size_t)j * D + base;
    for (int idx = threadIdx.x * 8; idx < 8192; idx += 256 * 8) {
        float4 w0 = *(const float4*)(wrow + idx);
        float4 w1 = *(const float4*)(wrow + idx + 4);
#pragma unroll
        for (int b = 0; b < BB; ++b) {
            uint4 yv = *(const uint4*)(y + (size_t)b * D + base + idx);
            union { u32 i; float f; } c[8];
            c[0].i = yv.x << 16; c[1].i = yv.x & 0xFFFF0000u;
            c[2].i = yv.y << 16; c[3].i = yv.y & 0xFFFF0000u;
            c[4].i = yv.z << 16; c[5].i = yv.z & 0xFFFF0000u;
            c[6].i = yv.w << 16; c[7].i = yv.w & 0xFFFF0000u;
            acc[b] = fmaf(w0.x, c[0].f, acc[b]);
            acc[b] = fmaf(w0.y, c[1].f, acc[b]);
            acc[b] = fmaf(w0.z, c[2].f, acc[b]);
            acc[b] = fmaf(w0.w, c[3].f, acc[b]);
            acc[b] = fmaf(w1.x, c[4].f, acc[b]);
            acc[b] = fmaf(w1.y, c[5].f, acc[b]);
            acc[b] = fmaf(w1.z, c[6].f, acc[b]);
            acc[b] = fmaf(w1.w, c[7].f, acc[b]);
        }
    }

    __shared__ float red[BB][4];
    const int lane = threadIdx.x & 63;
    const int w    = threadIdx.x >> 6;
#pragma unroll
    for (int b = 0; b < BB; ++b) {
        float v = acc[b];
        for (int off = 32; off > 0; off >>= 1) v += __shfl_down(v, off, 64);
        if (lane == 0) red[b][w] = v;
    }
    __syncthreads();
    if (threadIdx.x < BB) {
        const int b = threadIdx.x;
        h1p[blockIdx.y * (BB * 64) + b * 64 + j] =
            red[b][0] + red[b][1] + red[b][2] + red[b][3];
    }
}

// ---------------------------------------------------------------------------
// MLP layer 2 (+ slice-sum + layer-1 bias/ReLU). 1 block, 64 lanes.
// ---------------------------------------------------------------------------
__global__ void mlp2(const float* __restrict__ h1p,
                     const float* __restrict__ bm1,
                     const float* __restrict__ Wm2,
                     const float* __restrict__ bm2, float* __restrict__ out)
{
    const int lane = threadIdx.x;  // 0..63
    const float w    = Wm2[lane];
    const float b1   = bm1[lane];
    const float bias = bm2[0];
    for (int b = 0; b < BB; ++b) {
        float h = 0.f;
#pragma unroll
        for (int p = 0; p < 8; ++p) h += h1p[p * (BB * 64) + b * 64 + lane];
        float v = fmaxf(h + b1, 0.f) * w;
        for (int off = 32; off > 0; off >>= 1) v += __shfl_down(v, off, 64);
        if (lane == 0) out[b] = v + bias;
    }
}

// ---------------------------------------------------------------------------
extern "C" void kernel_launch(void* const* d_in, const int* in_sizes, int n_in,
                              void* d_out, int out_size, void* d_ws, size_t ws_size,
                              hipStream_t stream)
{
    const float* x   = (const float*)d_in[0];   // [8,16,4096]
    const float* Sc  = (const float*)d_in[1];   // [1,4096,4096]
    const float* Sl  = (const float*)d_in[2];   // [1,4096,4096]
    const float* Wc1 = (const float*)d_in[3];
    const float* bc1 = (const float*)d_in[4];
    const float* Wc2 = (const float*)d_in[5];
    const float* bc2 = (const float*)d_in[6];
    const float* Wl1 = (const float*)d_in[7];
    const float* bl1 = (const float*)d_in[8];
    const float* Wl2 = (const float*)d_in[9];
    const float* bl2 = (const float*)d_in[10];
    const float* Wm1 = (const float*)d_in[11];  // [64,65536]
    const float* bm1 = (const float*)d_in[12];
    const float* Wm2 = (const float*)d_in[13];  // [1,64]
    const float* bm2 = (const float*)d_in[14];
    float* out = (float*)d_out;                 // [8,1] f32

    char* ws = (char*)d_ws;                      // proven >= 81.02 MB
    u16*   part = (u16*)(ws);                    // 8 MB partial planes
    u16*   zb1  = (u16*)(ws + (8u  << 20));      // 2 MB
    u16*   yPa  = (u16*)(ws + (12u << 20));      // 2 MB
    u16*   yPb  = (u16*)(ws + (14u << 20));      // 2 MB
    float* h1p  = (float*)(ws + (16u << 20));    // 16 KB (8 slices x 8 x 64)
    u16*   Scb  = (u16*)(ws + (17u << 20));      // 32 MB
    u16*   Slb  = Scb + (size_t)NN * NN;         // 32 MB  (total 81.02 MB)

    const dim3 blk(256);
    const dim3 gridCmb(BB * NN / 256);           // 128
    const dim3 g2(64, 1, 8);                     // M=128: 512 blocks, 8 iters
    const dim3 g4(64, 2, 4);                     // M=256: 512 blocks, 16 iters
    const int  pl128 = 128 * NN;                 // plane elems, M=128
    const int  pl256 = 256 * NN;                 // plane elems, M=256

    cvt3<<<520, blk, 0, stream>>>(Sc, Scb, Sl, Slb, x, yPa);

    // Layer 1: clique, Fin=16 (M=128) -> Fout=32
    diffuse<8><<<g2, blk, 0, stream>>>(yPa, Scb, part);
    reduce_part<8><<<256, blk, 0, stream>>>(part, pl128, zb1);
    diffuse<8><<<g2, blk, 0, stream>>>(zb1, Scb, part);
    combine_relu<16, 32, 8><<<gridCmb, blk, 0, stream>>>(yPa, zb1, part, pl128,
                                                         Wc1, bc1, yPb);
    // Layer 2: clique, Fin=32 (M=256) -> Fout=16
    diffuse<16><<<g4, blk, 0, stream>>>(yPb, Scb, part);
    reduce_part<4><<<512, blk, 0, stream>>>(part, pl256, zb1);
    diffuse<16><<<g4, blk, 0, stream>>>(zb1, Scb, part);
    combine_relu<32, 16, 4><<<gridCmb, blk, 0, stream>>>(yPb, zb1, part, pl256,
                                                         Wc2, bc2, yPa);
    // Layer 3: line, Fin=16 (M=128) -> Fout=32
    diffuse<8><<<g2, blk, 0, stream>>>(yPa, Slb, part);
    reduce_part<8><<<256, blk, 0, stream>>>(part, pl128, zb1);
    diffuse<8><<<g2, blk, 0, stream>>>(zb1, Slb, part);
    combine_relu<16, 32, 8><<<gridCmb, blk, 0, stream>>>(yPa, zb1, part, pl128,
                                                         Wl1, bl1, yPb);
    // Layer 4: line, Fin=32 (M=256) -> Fout=16
    diffuse<16><<<g4, blk, 0, stream>>>(yPb, Slb, part);
    reduce_part<4><<<512, blk, 0, stream>>>(part, pl256, zb1);
    diffuse<16><<<g4, blk, 0, stream>>>(zb1, Slb, part);
    combine_relu<32, 16, 4><<<gridCmb, blk, 0, stream>>>(yPb, zb1, part, pl256,
                                                         Wl2, bl2, yPa);
    // MLP
    mlp1<<<dim3(64, 8), blk, 0, stream>>>(yPa, Wm1, h1p);
    mlp2<<<1, 64, 0, stream>>>(h1p, bm1, Wm2, bm2, out);
}

// Round 6
// 368.423 us; speedup vs baseline: 1.0445x; 1.0445x over previous
//
#include <hip/hip_runtime.h>

// SelectionGNN clique+line. I/O: float32. Internals: bf16 end-to-end with f32
// accumulation (MFMA + reduce). B=8, N=4096, E=1, K=3, F=[16,32,16],
// MLP 65536->64->1.
// R12: standalone S-conversion ELIMINATED (R8-R11: four cvt3 variants all
//     pinned at 55-67us regardless of schedule -> cut the traffic instead).
//     The first diffuse over each S reads S in f32 (reg-staged convert into
//     the swizzled LDS slots) and writes the bf16 tile through to Scb/Slb
//     as a byproduct (each element staged exactly once per dispatch).
//     Sc: 128 MB (cvt+reread) -> 96 MB in-dispatch; same for Sl.
//     Only x (2 MB) keeps a tiny standalone cvt. diffuse (6 dispatches)
//     unchanged R8 3-buffer counted-vmcnt pipeline.

#define NN 4096
#define BB 8

typedef unsigned short u16;
typedef unsigned int   u32;

typedef __attribute__((ext_vector_type(8))) short bf16x8;  // 8 bf16 = 4 VGPRs
typedef __attribute__((ext_vector_type(4))) float f32x4;

__device__ __forceinline__ u16 f2bf(float f) {
    union { float f; u32 i; } c; c.f = f;
    u32 i = c.i;
    u32 r = (i + 0x7FFFu + ((i >> 16) & 1u)) >> 16;  // RTNE
    return (u16)r;
}
__device__ __forceinline__ float bf2f(u16 u) {
    union { u32 i; float f; } c; c.i = ((u32)u) << 16; return c.f;
}
__device__ __forceinline__ u32 pack2bf(float lo, float hi) {
    return (u32)f2bf(lo) | ((u32)f2bf(hi) << 16);
}

__device__ __forceinline__ void gload_lds16(const u16* g, u16* l) {
    __builtin_amdgcn_global_load_lds(
        (__attribute__((address_space(1))) void*)g,
        (__attribute__((address_space(3))) void*)l, 16, 0, 0);
}

// ---------------------------------------------------------------------------
// x: 524288 f32 -> bf16. 256 blocks x 256 threads x 8 floats, one shot.
// ---------------------------------------------------------------------------
__global__ __launch_bounds__(256) void cvt_x(const float* __restrict__ in,
                                             u16* __restrict__ out)
{
    const int i = (blockIdx.x * 256 + threadIdx.x) * 8;
    float4 a = *(const float4*)(in + i);
    float4 b = *(const float4*)(in + i + 4);
    uint4 o;
    o.x = pack2bf(a.x, a.y); o.y = pack2bf(a.z, a.w);
    o.z = pack2bf(b.x, b.y); o.w = pack2bf(b.z, b.w);
    *(uint4*)(out + i) = o;
}

// ---------------------------------------------------------------------------
// Split-K diffusion with FUSED S conversion (first pass over each S):
//   Part[kz][r,n] = sum_k Z[r,k]*Sf[n,k];  Sb[n,k] = bf16(Sf[n,k])
// A staged via global_load_lds (Z already bf16). B reg-staged: 2x float4
// f32 loads per lane -> pack bf16x8 -> ds_write to the XOR-swizzled slot
// (slot gsl, source granule gsrc = gsl^rl, matching gload_lds layout) ->
// write-through to Sb. Plain 2-buffer __syncthreads pipeline (one-off).
// grid (64, 1, 8), M=128. Epilogue identical to diffuse.
// ---------------------------------------------------------------------------
template <int ITERS>
__global__ __launch_bounds__(256) void diffuse_cvtB(const u16* __restrict__ Z,
                                                    const float* __restrict__ Sf,
                                                    u16* __restrict__ Part,
                                                    u16* __restrict__ Sb)
{
    __shared__ u16 As[2 * 128 * 64];   // 32 KB
    __shared__ u16 Bs[2 * 64 * 64];    // 16 KB

    const int bx    = blockIdx.x;                   // 0..63
    const int ntile = ((bx & 7) << 3) | (bx >> 3);  // XCD swizzle
    const int nBase = ntile * 64;
    const int mBase = blockIdx.y * 128;
    const int tid   = threadIdx.x;
    const int lane  = tid & 63;
    const int wv    = tid >> 6;
    const int quad  = lane >> 4;
    const int l16   = lane & 15;

    const int kStart = (int)blockIdx.z * (ITERS * 64);

    const int rl   = lane >> 3;        // row within 8-row group
    const int gsl  = lane & 7;         // dest granule slot
    const int gsrc = gsl ^ rl;         // source granule (XOR swizzle)

    f32x4 acc[2][4];
#pragma unroll
    for (int i = 0; i < 2; ++i)
#pragma unroll
        for (int j = 0; j < 4; ++j) acc[i][j] = (f32x4){0.f, 0.f, 0.f, 0.f};

    auto stageA = [&](int buf, int k0) {
#pragma unroll
        for (int j = 0; j < 4; ++j) {
            const int rb = (wv * 4 + j) * 8;   // 0..120
            gload_lds16(Z + (size_t)(mBase + rb + rl) * NN + k0 + gsrc * 8,
                        &As[buf * 8192 + rb * 64]);
        }
    };

    float4 fB[2][2];
    auto loadB = [&](int k0) {
#pragma unroll
        for (int j = 0; j < 2; ++j) {
            const int row = nBase + (wv * 2 + j) * 8 + rl;
            const float* p = Sf + (size_t)row * NN + k0 + gsrc * 8;
            fB[j][0] = *(const float4*)p;
            fB[j][1] = *(const float4*)(p + 4);
        }
    };
    auto writeB = [&](int buf, int k0) {
#pragma unroll
        for (int j = 0; j < 2; ++j) {
            const int rloc = (wv * 2 + j) * 8 + rl;       // 0..63 within tile
            bf16x8 v;
            v[0] = (short)f2bf(fB[j][0].x); v[1] = (short)f2bf(fB[j][0].y);
            v[2] = (short)f2bf(fB[j][0].z); v[3] = (short)f2bf(fB[j][0].w);
            v[4] = (short)f2bf(fB[j][1].x); v[5] = (short)f2bf(fB[j][1].y);
            v[6] = (short)f2bf(fB[j][1].z); v[7] = (short)f2bf(fB[j][1].w);
            *(bf16x8*)&Bs[buf * 4096 + rloc * 64 + gsl * 8] = v;
            *(bf16x8*)&Sb[(size_t)(nBase + rloc) * NN + k0 + gsrc * 8] = v;
        }
    };

    auto compute = [&](int buf) {
#pragma unroll
        for (int s = 0; s < 2; ++s) {
            const int g = s * 4 + quad;        // k-granule 0..7
            bf16x8 af[2], bf[4];
#pragma unroll
            for (int mi = 0; mi < 2; ++mi) {
                const int r = wv * 32 + mi * 16 + l16;
                af[mi] = *(const bf16x8*)&As[buf * 8192 + r * 64 + ((g ^ (r & 7)) << 3)];
            }
#pragma unroll
            for (int ni = 0; ni < 4; ++ni) {
                const int r = ni * 16 + l16;
                bf[ni] = *(const bf16x8*)&Bs[buf * 4096 + r * 64 + ((g ^ (r & 7)) << 3)];
            }
#pragma unroll
            for (int mi = 0; mi < 2; ++mi)
#pragma unroll
                for (int ni = 0; ni < 4; ++ni)
                    acc[mi][ni] = __builtin_amdgcn_mfma_f32_16x16x32_bf16(
                        af[mi], bf[ni], acc[mi][ni], 0, 0, 0);
        }
    };

    // prologue: fill buffer 0
    loadB(kStart);
    stageA(0, kStart);
    writeB(0, kStart);
    __syncthreads();

#pragma unroll
    for (int i = 0; i < ITERS; ++i) {
        const int cur = i & 1;
        if (i + 1 < ITERS) {
            stageA(cur ^ 1, kStart + (i + 1) * 64);   // async -> LDS
            loadB(kStart + (i + 1) * 64);             // f32 -> regs
        }
        compute(cur);                                  // MFMA on current
        if (i + 1 < ITERS) writeB(cur ^ 1, kStart + (i + 1) * 64);
        __syncthreads();                               // drains vm+lgkm
    }

    // Per-wave transpose region: 32 rows x 72 u16 (144B rows, 16B-aligned).
    // D mapping: col = lane&15, row = quad*4 + reg.
    u16* tb = &As[wv * 2304];
#pragma unroll
    for (int mi = 0; mi < 2; ++mi)
#pragma unroll
        for (int ni = 0; ni < 4; ++ni)
#pragma unroll
            for (int i = 0; i < 4; ++i)
                tb[(mi * 16 + quad * 4 + i) * 72 + ni * 16 + l16] =
                    f2bf(acc[mi][ni][i]);

    const size_t plane = (size_t)gridDim.y * 128 * NN;
    u16* pp = Part + (size_t)blockIdx.z * plane;
    const int row0g = mBase + wv * 32;
#pragma unroll
    for (int j = 0; j < 4; ++j) {
        const int r = (lane >> 3) + j * 8;      // 0..31
        const int c = (lane & 7) * 8;           // 0..56
        bf16x8 v = *(const bf16x8*)&tb[r * 72 + c];
        *(bf16x8*)&pp[(size_t)(row0g + r) * NN + nBase + c] = v;
    }
}

// ---------------------------------------------------------------------------
// Split-K diffusion, 128(M) x 64(N) tile, BK=64, bf16 A/B via async LDS:
//   Part[kz][r,n] = sum_{k in slice} Z[r,k] * S[n,k]   (bf16 partial planes)
// LDS unpadded, XOR-swizzled 16B granules: slot(r,g) = g ^ (r&7).
// Pipeline (depth 2, 3 buffers, 72 KB -> 2 blocks/CU = grid co-residency):
//   per iter i: STAGE(i+2) ; s_waitcnt vmcnt(12) ; s_barrier ; COMPUTE(i) ;
//   s_barrier.  Counted vmcnt keeps 2 staged tiles in flight across barriers
//   (T4). Fully unrolled via template ITERS (8 or 16).
// Epilogue: per-wave LDS transpose then 4x global_store_dwordx4 per lane.
// grid: (64, M/128, KS). blockIdx.x XCD-swizzled. 4 waves stacked in M; wave
// owns 32x64 via 2x4 mfma_f32_16x16x32_bf16.
// ---------------------------------------------------------------------------
template <int ITERS>
__global__ __launch_bounds__(256) void diffuse(const u16* __restrict__ Z,
                                               const u16* __restrict__ S,
                                               u16* __restrict__ Part)
{
    __shared__ u16 As[3 * 128 * 64];   // 3 x 16 KB, swizzled
    __shared__ u16 Bs[3 * 64 * 64];    // 3 x  8 KB, swizzled

    const int bx    = blockIdx.x;                   // 0..63
    const int ntile = ((bx & 7) << 3) | (bx >> 3);  // XCD swizzle
    const int nBase = ntile * 64;
    const int mBase = blockIdx.y * 128;
    const int tid   = threadIdx.x;
    const int lane  = tid & 63;
    const int wv    = tid >> 6;
    const int quad  = lane >> 4;
    const int l16   = lane & 15;

    const int kStart = (int)blockIdx.z * (ITERS * 64);

    // async staging: wave-issue = 64 lanes x 16 B = 8 rows x 8 granules
    const int rl   = lane >> 3;        // row within 8-row group
    const int gsl  = lane & 7;         // dest granule slot
    const int gsrc = gsl ^ rl;         // source granule (XOR swizzle)

    f32x4 acc[2][4];
#pragma unroll
    for (int i = 0; i < 2; ++i)
#pragma unroll
        for (int j = 0; j < 4; ++j) acc[i][j] = (f32x4){0.f, 0.f, 0.f, 0.f};

    auto stage = [&](int buf, int k0) {
#pragma unroll
        for (int j = 0; j < 4; ++j) {
            const int rb = (wv * 4 + j) * 8;   // 0..120
            gload_lds16(Z + (size_t)(mBase + rb + rl) * NN + k0 + gsrc * 8,
                        &As[buf * 8192 + rb * 64]);
        }
#pragma unroll
        for (int j = 0; j < 2; ++j) {
            const int rb = (wv * 2 + j) * 8;   // 0..56
            gload_lds16(S + (size_t)(nBase + rb + rl) * NN + k0 + gsrc * 8,
                        &Bs[buf * 4096 + rb * 64]);
        }
    };

    auto compute = [&](int buf) {
#pragma unroll
        for (int s = 0; s < 2; ++s) {
            const int g = s * 4 + quad;        // k-granule 0..7
            bf16x8 af[2], bf[4];
#pragma unroll
            for (int mi = 0; mi < 2; ++mi) {
                const int r = wv * 32 + mi * 16 + l16;
                af[mi] = *(const bf16x8*)&As[buf * 8192 + r * 64 + ((g ^ (r & 7)) << 3)];
            }
#pragma unroll
            for (int ni = 0; ni < 4; ++ni) {
                const int r = ni * 16 + l16;
                bf[ni] = *(const bf16x8*)&Bs[buf * 4096 + r * 64 + ((g ^ (r & 7)) << 3)];
            }
#pragma unroll
            for (int mi = 0; mi < 2; ++mi)
#pragma unroll
                for (int ni = 0; ni < 4; ++ni)
                    acc[mi][ni] = __builtin_amdgcn_mfma_f32_16x16x32_bf16(
                        af[mi], bf[ni], acc[mi][ni], 0, 0, 0);
        }
    };

    // prologue: two tiles in flight before first wait
    stage(0, kStart);
    stage(1, kStart + 64);

#pragma unroll
    for (int i = 0; i < ITERS; ++i) {
        if (i + 2 < ITERS) stage((i + 2) % 3, kStart + (i + 2) * 64);
        if (i < ITERS - 2)
            asm volatile("s_waitcnt vmcnt(12)" ::: "memory");  // stage(i) landed
        else if (i == ITERS - 2)
            asm volatile("s_waitcnt vmcnt(6)" ::: "memory");
        else
            asm volatile("s_waitcnt vmcnt(0)" ::: "memory");
        __builtin_amdgcn_s_barrier();          // raw barrier: no vmcnt drain
        compute(i % 3);
        if (i + 1 < ITERS) __builtin_amdgcn_s_barrier();  // guard buf reuse
    }

    // Epilogue: all waves done with LDS reads before we reuse As as scratch.
    asm volatile("s_waitcnt lgkmcnt(0)" ::: "memory");
    __builtin_amdgcn_s_barrier();

    // Per-wave transpose region: 32 rows x 72 u16 (144B rows, 16B-aligned).
    // D mapping: col = lane&15, row = quad*4 + reg.
    u16* tb = &As[wv * 2304];
#pragma unroll
    for (int mi = 0; mi < 2; ++mi)
#pragma unroll
        for (int ni = 0; ni < 4; ++ni)
#pragma unroll
            for (int i = 0; i < 4; ++i)
                tb[(mi * 16 + quad * 4 + i) * 72 + ni * 16 + l16] =
                    f2bf(acc[mi][ni][i]);

    const size_t plane = (size_t)gridDim.y * 128 * NN;
    u16* pp = Part + (size_t)blockIdx.z * plane;
    const int row0g = mBase + wv * 32;
#pragma unroll
    for (int j = 0; j < 4; ++j) {
        const int r = (lane >> 3) + j * 8;      // 0..31
        const int c = (lane & 7) * 8;           // 0..56
        bf16x8 v = *(const bf16x8*)&tb[r * 72 + c];
        *(bf16x8*)&pp[(size_t)(row0g + r) * NN + nBase + c] = v;
    }
}

// ---------------------------------------------------------------------------
// Sum KS bf16 partial planes (f32 accumulate) -> bf16 z.  (z1 only.)
// Vectorized 8 bf16 (uint4) per thread-iter.
// ---------------------------------------------------------------------------
template <int KS>
__global__ __launch_bounds__(256) void reduce_part(const u16* __restrict__ part,
                                                   int planeElems,
                                                   u16* __restrict__ outb)
{
    const int base   = (blockIdx.x * 256 + threadIdx.x) * 8;
    const int stride = gridDim.x * 256 * 8;
    for (int i = base; i < planeElems; i += stride) {
        float s[8];
#pragma unroll
        for (int e = 0; e < 8; ++e) s[e] = 0.f;
#pragma unroll
        for (int p = 0; p < KS; ++p) {
            uint4 v = *(const uint4*)(part + (size_t)p * planeElems + i);
            const u32 w[4] = {v.x, v.y, v.z, v.w};
#pragma unroll
            for (int q = 0; q < 4; ++q) {
                union { u32 i; float f; } lo, hi;
                lo.i = w[q] << 16;
                hi.i = w[q] & 0xFFFF0000u;
                s[q * 2]     += lo.f;
                s[q * 2 + 1] += hi.f;
            }
        }
        uint4 o;
        o.x = (u32)f2bf(s[0]) | ((u32)f2bf(s[1]) << 16);
        o.y = (u32)f2bf(s[2]) | ((u32)f2bf(s[3]) << 16);
        o.z = (u32)f2bf(s[4]) | ((u32)f2bf(s[5]) << 16);
        o.w = (u32)f2bf(s[6]) | ((u32)f2bf(s[7]) << 16);
        *(uint4*)(outb + i) = o;
    }
}

// ---------------------------------------------------------------------------
// Tap combine + ReLU, bf16 in/out (f32 math). Tap 2 is read directly from
// the KS bf16 partial planes (fused reduce, f32-exact inside):
// out[b,g,n] = relu( bias[g] + sum_k sum_f W[g,k,f] * z_k[b,f,n] )
// ---------------------------------------------------------------------------
template <int FIN, int FOUT, int KS>
__global__ __launch_bounds__(256) void combine_relu(
    const u16* __restrict__ z0, const u16* __restrict__ z1,
    const u16* __restrict__ part2, int planeElems,
    const float* __restrict__ W, const float* __restrict__ bias,
    u16* __restrict__ out)
{
    __shared__ float hs[FOUT * 3 * FIN];
    __shared__ float bs[FOUT];
    for (int i = threadIdx.x; i < FOUT * 3 * FIN; i += 256) hs[i] = W[i];
    if (threadIdx.x < FOUT) bs[threadIdx.x] = bias[threadIdx.x];
    __syncthreads();

    const int nb = NN / 256;                 // 16
    const int b  = blockIdx.x / nb;
    const int n  = (blockIdx.x % nb) * 256 + threadIdx.x;

    float zv[3][FIN];
    const u16* zp0 = z0 + (size_t)b * FIN * NN + n;
    const u16* zp1 = z1 + (size_t)b * FIN * NN + n;
    const u16* zp2 = part2 + (size_t)b * FIN * NN + n;
#pragma unroll
    for (int f = 0; f < FIN; ++f) {
        zv[0][f] = bf2f(zp0[(size_t)f * NN]);
        zv[1][f] = bf2f(zp1[(size_t)f * NN]);
        float s = 0.f;
#pragma unroll
        for (int p = 0; p < KS; ++p)
            s += bf2f(zp2[(size_t)p * planeElems + (size_t)f * NN]);
        zv[2][f] = s;
    }

    u16* op = out + (size_t)b * FOUT * NN + n;
    for (int g = 0; g < FOUT; ++g) {
        float acc = bs[g];
#pragma unroll
        for (int k = 0; k < 3; ++k)
#pragma unroll
            for (int f = 0; f < FIN; ++f)
                acc = fmaf(hs[(g * 3 + k) * FIN + f], zv[k][f], acc);
        op[(size_t)g * NN] = f2bf(fmaxf(acc, 0.f));
    }
}

// ---------------------------------------------------------------------------
// MLP layer 1, split-K: h1p[slice][b][j] = sum_{slice} y[b,i]*Wm1[j,i].
// y is bf16; Wm1 f32. grid: (64, 8). Plain stores (no atomics, no memset);
// mlp2 sums the 8 slices and applies bias+ReLU.
// ---------------------------------------------------------------------------
__global__ __launch_bounds__(256) void mlp1(const u16* __restrict__ y,
                                            const float* __restrict__ Wm1,
                                            float* __restrict__ h1p)
{
    const int j    = blockIdx.x;
    const int base = blockIdx.y * 8192;
    const int D    = 16 * NN;  // 65536

    float acc[BB];
#pragma unroll
    for (int b = 0; b < BB; ++b) acc[b] = 0.f;

    const float* wrow = Wm1 + (size_t)j * D + base;
    for (int idx = threadIdx.x * 8; idx < 8192; idx += 256 * 8) {
        float4 w0 = *(const float4*)(wrow + idx);
        float4 w1 = *(const float4*)(wrow + idx + 4);
#pragma unroll
        for (int b = 0; b < BB; ++b) {
            uint4 yv = *(const uint4*)(y + (size_t)b * D + base + idx);
            union { u32 i; float f; } c[8];
            c[0].i = yv.x << 16; c[1].i = yv.x & 0xFFFF0000u;
            c[2].i = yv.y << 16; c[3].i = yv.y & 0xFFFF0000u;
            c[4].i = yv.z << 16; c[5].i = yv.z & 0xFFFF0000u;
            c[6].i = yv.w << 16; c[7].i = yv.w & 0xFFFF0000u;
            acc[b] = fmaf(w0.x, c[0].f, acc[b]);
            acc[b] = fmaf(w0.y, c[1].f, acc[b]);
            acc[b] = fmaf(w0.z, c[2].f, acc[b]);
            acc[b] = fmaf(w0.w, c[3].f, acc[b]);
            acc[b] = fmaf(w1.x, c[4].f, acc[b]);
            acc[b] = fmaf(w1.y, c[5].f, acc[b]);
            acc[b] = fmaf(w1.z, c[6].f, acc[b]);
            acc[b] = fmaf(w1.w, c[7].f, acc[b]);
        }
    }

    __shared__ float red[BB][4];
    const int lane = threadIdx.x & 63;
    const int w    = threadIdx.x >> 6;
#pragma unroll
    for (int b = 0; b < BB; ++b) {
        float v = acc[b];
        for (int off = 32; off > 0; off >>= 1) v += __shfl_down(v, off, 64);
        if (lane == 0) red[b][w] = v;
    }
    __syncthreads();
    if (threadIdx.x < BB) {
        const int b = threadIdx.x;
        h1p[blockIdx.y * (BB * 64) + b * 64 + j] =
            red[b][0] + red[b][1] + red[b][2] + red[b][3];
    }
}

// ---------------------------------------------------------------------------
// MLP layer 2 (+ slice-sum + layer-1 bias/ReLU). 1 block, 64 lanes.
// ---------------------------------------------------------------------------
__global__ void mlp2(const float* __restrict__ h1p,
                     const float* __restrict__ bm1,
                     const float* __restrict__ Wm2,
                     const float* __restrict__ bm2, float* __restrict__ out)
{
    const int lane = threadIdx.x;  // 0..63
    const float w    = Wm2[lane];
    const float b1   = bm1[lane];
    const float bias = bm2[0];
    for (int b = 0; b < BB; ++b) {
        float h = 0.f;
#pragma unroll
        for (int p = 0; p < 8; ++p) h += h1p[p * (BB * 64) + b * 64 + lane];
        float v = fmaxf(h + b1, 0.f) * w;
        for (int off = 32; off > 0; off >>= 1) v += __shfl_down(v, off, 64);
        if (lane == 0) out[b] = v + bias;
    }
}

// ---------------------------------------------------------------------------
extern "C" void kernel_launch(void* const* d_in, const int* in_sizes, int n_in,
                              void* d_out, int out_size, void* d_ws, size_t ws_size,
                              hipStream_t stream)
{
    const float* x   = (const float*)d_in[0];   // [8,16,4096]
    const float* Sc  = (const float*)d_in[1];   // [1,4096,4096]
    const float* Sl  = (const float*)d_in[2];   // [1,4096,4096]
    const float* Wc1 = (const float*)d_in[3];
    const float* bc1 = (const float*)d_in[4];
    const float* Wc2 = (const float*)d_in[5];
    const float* bc2 = (const float*)d_in[6];
    const float* Wl1 = (const float*)d_in[7];
    const float* bl1 = (const float*)d_in[8];
    const float* Wl2 = (const float*)d_in[9];
    const float* bl2 = (const float*)d_in[10];
    const float* Wm1 = (const float*)d_in[11];  // [64,65536]
    const float* bm1 = (const float*)d_in[12];
    const float* Wm2 = (const float*)d_in[13];  // [1,64]
    const float* bm2 = (const float*)d_in[14];
    float* out = (float*)d_out;                 // [8,1] f32

    char* ws = (char*)d_ws;                      // proven >= 81.02 MB
    u16*   part = (u16*)(ws);                    // 8 MB partial planes
    u16*   zb1  = (u16*)(ws + (8u  << 20));      // 2 MB
    u16*   yPa  = (u16*)(ws + (12u << 20));      // 2 MB
    u16*   yPb  = (u16*)(ws + (14u << 20));      // 2 MB
    float* h1p  = (float*)(ws + (16u << 20));    // 16 KB (8 slices x 8 x 64)
    u16*   Scb  = (u16*)(ws + (17u << 20));      // 32 MB
    u16*   Slb  = Scb + (size_t)NN * NN;         // 32 MB  (total 81.02 MB)

    const dim3 blk(256);
    const dim3 gridCmb(BB * NN / 256);           // 128
    const dim3 g2(64, 1, 8);                     // M=128: 512 blocks, 8 iters
    const dim3 g4(64, 2, 4);                     // M=256: 512 blocks, 16 iters
    const int  pl128 = 128 * NN;                 // plane elems, M=128
    const int  pl256 = 256 * NN;                 // plane elems, M=256

    cvt_x<<<256, blk, 0, stream>>>(x, yPa);

    // Layer 1: clique, Fin=16 (M=128) -> Fout=32.  First pass over Sc reads
    // f32 and writes Scb as byproduct.
    diffuse_cvtB<8><<<g2, blk, 0, stream>>>(yPa, Sc, part, Scb);
    reduce_part<8><<<256, blk, 0, stream>>>(part, pl128, zb1);
    diffuse<8><<<g2, blk, 0, stream>>>(zb1, Scb, part);
    combine_relu<16, 32, 8><<<gridCmb, blk, 0, stream>>>(yPa, zb1, part, pl128,
                                                         Wc1, bc1, yPb);
    // Layer 2: clique, Fin=32 (M=256) -> Fout=16
    diffuse<16><<<g4, blk, 0, stream>>>(yPb, Scb, part);
    reduce_part<4><<<512, blk, 0, stream>>>(part, pl256, zb1);
    diffuse<16><<<g4, blk, 0, stream>>>(zb1, Scb, part);
    combine_relu<32, 16, 4><<<gridCmb, blk, 0, stream>>>(yPb, zb1, part, pl256,
                                                         Wc2, bc2, yPa);
    // Layer 3: line, Fin=16 (M=128) -> Fout=32.  First pass over Sl reads
    // f32 and writes Slb as byproduct.
    diffuse_cvtB<8><<<g2, blk, 0, stream>>>(yPa, Sl, part, Slb);
    reduce_part<8><<<256, blk, 0, stream>>>(part, pl128, zb1);
    diffuse<8><<<g2, blk, 0, stream>>>(zb1, Slb, part);
    combine_relu<16, 32, 8><<<gridCmb, blk, 0, stream>>>(yPa, zb1, part, pl128,
                                                         Wl1, bl1, yPb);
    // Layer 4: line, Fin=32 (M=256) -> Fout=16
    diffuse<16><<<g4, blk, 0, stream>>>(yPb, Slb, part);
    reduce_part<4><<<512, blk, 0, stream>>>(part, pl256, zb1);
    diffuse<16><<<g4, blk, 0, stream>>>(zb1, Slb, part);
    combine_relu<32, 16, 4><<<gridCmb, blk, 0, stream>>>(yPb, zb1, part, pl256,
                                                         Wl2, bl2, yPa);
    // MLP
    mlp1<<<dim3(64, 8), blk, 0, stream>>>(yPa, Wm1, h1p);
    mlp2<<<1, 64, 0, stream>>>(h1p, bm1, Wm2, bm2, out);
}